// Round 14
// baseline (90.545 us; speedup 1.0000x reference)
//
#include <hip/hip_runtime.h>
#include <hip/hip_bf16.h>
#include <float.h>

// Problem constants
#define BATCH 8
#define CHN   64
#define HW    56
#define PIX   3136          // 56*56
#define LDB   72            // band LDS stride in bf16 elems (144 B, 16-B aligned)
#define DSTR  16            // dots row stride (doubles): slots 0..12 used
#define QW    14            // pixels per dots block (quarter row)
#define QC    18            // tile cols (QW + 4 halo)
#define NLOC  54            // 3 rows x 18 cols
#define NST   68            // nbr fp32 tile stride (floats): 16-B aligned, +4 banks/local
#define CST   66            // ctr fp64 tile stride (doubles): 16-B aligned, +2 bank-quads

typedef __bf16 bf16x8 __attribute__((ext_vector_type(8)));
typedef float  f32x4  __attribute__((ext_vector_type(4)));

static __device__ __forceinline__ unsigned short f2bf(float f) {
    unsigned int u = __float_as_uint(f);
    u += 0x7fffu + ((u >> 16) & 1u);          // round-to-nearest-even
    return (unsigned short)(u >> 16);
}

// ---------------------------------------------------------------------------
// Stage 1: dots[b][p][s], s=0..12 (13 unique slots; others are exact mirrors
// read as dots[q][24-s] downstream). fp64 products, c=0..63 sequential —
// bit-identical keys to the verified R1/R9/R12 kernels.
// R14: issue-count attack (R13 showed occupancy-insensitivity; R12 showed
// issue cuts pay). Two tiles: ctr row in fp64 (cvt ONCE at staging: 896
// cvts/block vs R13's 23K in compute threads) + nbr band in fp32 (cvt
// per-use). Compute thread (s,jl): 32 ctr double2-b128 + 16 nbr float4-b128
// + 64 cvt + 64 f64 FMA -> per-wave ~640 cyc vs R13 ~900.
// t<224 emits bf16 xT (uint2); s==12 emits invn; blocks 1792+ pack wbf.
// ---------------------------------------------------------------------------
__global__ __launch_bounds__(256) void dots_kernel(const float* __restrict__ x,
                                                   const float* __restrict__ w,
                                                   double* __restrict__ dots,
                                                   double* __restrict__ invn,
                                                   unsigned short* __restrict__ wbf,
                                                   unsigned short* __restrict__ xT) {
    const int blk = blockIdx.x;
    const int t = threadIdx.x;
    if (blk >= 1792) {                            // 16 tail blocks: pack wbf
        int wi = (blk - 1792) * 256 + t;          // 0..4095
        #pragma unroll
        for (int k = 0; k < 9; k++) {
            int l = wi + k * 4096;                // l = (o*9+tap)*64 + c
            int otap = l >> 6, c = l & 63;
            int o = otap / 9, tap = otap - o * 9;
            wbf[l] = f2bf(w[(o * CHN + c) * 9 + tap]);
        }
        return;
    }
    const int quarter = blk & 3;
    const int r = (blk >> 2) % HW;
    const int b = blk / 224;
    const int jbase = quarter * QW;

    __shared__ float  nbr32[NLOC * NST];          // 14.7 KB: [local][c] fp32
    __shared__ double ctr64[QW * CST];            // 7.4 KB:  [jl][c] fp64 (row r)
    // stage rows r-2..r, cols jbase-2..jbase+15 (zero-padded OOB)
    const float* xb = x + (size_t)b * CHN * PIX;
    for (int l = t; l < NLOC * CHN; l += 256) {
        int c = l / NLOC, rem = l - c * NLOC;
        int lr = rem / QC, lc = rem - lr * QC;
        int row = r - 2 + lr;
        int col = jbase - 2 + lc;
        float v = 0.0f;
        if (row >= 0 && row < HW && col >= 0 && col < HW)
            v = xb[(size_t)c * PIX + row * HW + col];
        nbr32[rem * NST + c] = v;
        if (lr == 2 && lc >= 2 && lc < 16)        // center row, interior cols
            ctr64[(lc - 2) * CST + c] = (double)v;
    }
    __syncthreads();

    // xT emit: t<224: jl = t>>4 (0..13), oct = t&15 -> 4 channels
    if (t < 224) {
        const int jl = t >> 4, oct = t & 15;
        const float* src = &nbr32[(2 * QC + 2 + jl) * NST + oct * 4];
        float2 f0 = *(const float2*)(src);
        float2 f1 = *(const float2*)(src + 2);
        uint2 pk;
        pk.x = (unsigned int)f2bf(f0.x) | ((unsigned int)f2bf(f0.y) << 16);
        pk.y = (unsigned int)f2bf(f1.x) | ((unsigned int)f2bf(f1.y) << 16);
        *(uint2*)(xT + ((size_t)b * PIX + r * HW + jbase + jl) * CHN + oct * 4) = pk;
    }

    if (t >= 182) return;
    const int s = t / QW;                         // 0..12
    const int jl = t - s * QW;                    // local col 0..13
    const int lr = s / 5;                         // dr = lr-2 in {-2,-1,0}
    const int dc = s % 5 - 2;
    const double* cp = &ctr64[jl * CST];
    const float*  np = &nbr32[(lr * QC + jl + dc + 2) * NST];

    double acc = 0.0;
    #pragma unroll 4
    for (int k = 0; k < 16; k++) {                // 4 channels per iter
        double2 c0 = *(const double2*)(cp + 4 * k);
        double2 c1 = *(const double2*)(cp + 4 * k + 2);
        f32x4  nv = *(const f32x4*)(np + 4 * k);
        acc += c0.x * (double)nv.x;               // c = 4k   (sequential order)
        acc += c0.y * (double)nv.y;               // c = 4k+1
        acc += c1.x * (double)nv.z;               // c = 4k+2
        acc += c1.y * (double)nv.w;               // c = 4k+3
    }
    const int p = r * HW + jbase + jl;
    dots[((size_t)b * PIX + p) * DSTR + s] = acc;
    if (s == 12) invn[(size_t)b * PIX + p] = 1.0 / sqrt(acc);
}

// ---------------------------------------------------------------------------
// Stage 2 (fused select + gather-conv), per (b, image row r).  [R12-verified]
// Wave 0 (t<56): 25 keys — s<13 direct, s>=13 mirror dots[q][24-s] (exact:
// IEEE mul commutes) * invn[q], DBL_MAX invalid; 9-rank stable select +
// ascending index sort -> qtab. t in [56,64): zero qtab tail. t>=64: stage
// bf16 band from xT via uint4. Then indexed-ds_read_b128 MFMA, direct out.
// ---------------------------------------------------------------------------
__global__ __launch_bounds__(256) void fused_kernel(const unsigned short* __restrict__ xT,
                                                    const double* __restrict__ dots,
                                                    const double* __restrict__ invn,
                                                    const unsigned short* __restrict__ wbf,
                                                    float* __restrict__ out) {
    const int b = blockIdx.y;
    const int r = blockIdx.x;
    __shared__ unsigned short band[300 * LDB];
    __shared__ int qtab[9 * 64];
    const int t = threadIdx.x;

    // A-fragments (registers; b128 loads from packed wbf)
    const int wv = t >> 6, ln = t & 63;
    const int mrow = ln & 15, kq = ln >> 4;
    const int o = wv * 16 + mrow;
    bf16x8 afr[9][2];
    #pragma unroll
    for (int tap = 0; tap < 9; tap++) {
        #pragma unroll
        for (int hf = 0; hf < 2; hf++) {
            afr[tap][hf] = *(const bf16x8*)(wbf + (size_t)(o * 9 + tap) * 64 + hf * 32 + kq * 8);
        }
    }

    if (t < 56) {
        const int jj = t;
        const double* dp  = dots + ((size_t)b * PIX + r * HW + jj) * DSTR;
        const double* inb = invn + (size_t)b * PIX;
        double k2[25];
        #pragma unroll
        for (int s = 0; s < 25; s++) {
            int dr = s / 5 - 2, dc = s % 5 - 2;
            int qi = r + dr, qj = jj + dc;
            bool valid = qi >= 0 && qi < HW && qj >= 0 && qj < HW;
            int q = qi * HW + qj;
            double raw;
            if (s < 13) raw = dp[s];
            else        raw = valid ? dots[((size_t)b * PIX + q) * DSTR + (24 - s)] : 0.0;
            k2[s] = valid ? raw * inb[q] : DBL_MAX;
        }
        unsigned int used = 0;
        int bq[9];
        #pragma unroll
        for (int rr = 0; rr < 9; rr++) {
            double best = DBL_MAX; int bs = 0;
            #pragma unroll
            for (int s = 0; s < 25; s++) {
                bool ok = (((used >> s) & 1u) == 0u) && (k2[s] < best);
                if (ok) { best = k2[s]; bs = s; }
            }
            used |= (1u << bs);
            bq[rr] = (r + bs / 5 - 2) * HW + (jj + bs % 5 - 2);
        }
        #pragma unroll
        for (int a = 0; a < 8; a++) {
            #pragma unroll
            for (int c2 = 0; c2 < 8 - a; c2++) {
                int u = bq[c2], v = bq[c2 + 1];
                bq[c2] = u < v ? u : v; bq[c2 + 1] = u < v ? v : u;
            }
        }
        #pragma unroll
        for (int k = 0; k < 9; k++) {
            int q = bq[k], qi = q / HW, qj = q - qi * HW;
            qtab[k * 64 + jj] = ((qi - r + 2) * 60 + qj + 2) * LDB;
        }
    } else if (t < 64) {
        #pragma unroll
        for (int k = 0; k < 9; k++) qtab[k * 64 + t] = 0;   // tail dummy
    } else {
        // band: 300 locals x 8 ch-octs, uint4 both sides
        for (int l = t - 64; l < 2400; l += 192) {
            int local = l >> 3, ch8 = l & 7;
            int lr = local / 60, col = local - lr * 60 - 2;
            int row = r - 2 + lr;
            uint4 v = {0, 0, 0, 0};
            if (row >= 0 && row < HW && col >= 0 && col < HW)
                v = *(const uint4*)(xT + ((size_t)b * PIX + row * HW + col) * CHN + ch8 * 8);
            *(uint4*)(&band[local * LDB + ch8 * 8]) = v;
        }
    }
    __syncthreads();

    // MFMA gather-conv (verified R5/R8/R9/R12)
    f32x4 oacc[4] = {{0,0,0,0},{0,0,0,0},{0,0,0,0},{0,0,0,0}};
    #pragma unroll
    for (int tap = 0; tap < 9; tap++) {
        #pragma unroll
        for (int nt = 0; nt < 4; nt++) {
            int q = qtab[tap * 64 + nt * 16 + mrow];
            const unsigned short* bp = &band[q + kq * 8];
            bf16x8 b0 = *(const bf16x8*)bp;
            bf16x8 b1 = *(const bf16x8*)(bp + 32);
            oacc[nt] = __builtin_amdgcn_mfma_f32_16x16x32_bf16(afr[tap][0], b0, oacc[nt], 0, 0, 0);
            oacc[nt] = __builtin_amdgcn_mfma_f32_16x16x32_bf16(afr[tap][1], b1, oacc[nt], 0, 0, 0);
        }
    }
    // C/D: col = lane&15 = p-within-tile, row = kq*4+rg = o-within-strip
    float* ob = out + ((size_t)b * 64 + wv * 16 + kq * 4) * PIX + r * HW;
    #pragma unroll
    for (int nt = 0; nt < 4; nt++) {
        int p = nt * 16 + mrow;
        if (p < HW) {
            #pragma unroll
            for (int rg = 0; rg < 4; rg++) ob[(size_t)rg * PIX + p] = oacc[nt][rg];
        }
    }
}

// ---------------------------------------------------------------------------
// Workspace layout (total ~6.7 MB):
//   dots : 25088 * 16 * 8 = 3,211,264 B @ 0
//   invn : 25088 * 8      =   200,704 B @ 3,211,264
//   wbf  : 64*9*64 * 2    =    73,728 B @ 3,411,968
//   xT   : 8*3136*64 * 2  = 3,211,264 B @ 3,485,696
// ---------------------------------------------------------------------------
extern "C" void kernel_launch(void* const* d_in, const int* in_sizes, int n_in,
                              void* d_out, int out_size, void* d_ws, size_t ws_size,
                              hipStream_t stream) {
    const float* x = (const float*)d_in[0];
    const float* w = (const float*)d_in[1];
    float* out = (float*)d_out;
    char* ws = (char*)d_ws;
    double*         dots = (double*)ws;
    double*         invn = (double*)(ws + 3211264);
    unsigned short* wbf  = (unsigned short*)(ws + 3411968);
    unsigned short* xT   = (unsigned short*)(ws + 3485696);

    // 1792 blocks cover (b,r,quarter); 16 tail blocks pack wbf
    dots_kernel<<<1808, 256, 0, stream>>>(x, w, dots, invn, wbf, xT);
    fused_kernel<<<dim3(56, 8), 256, 0, stream>>>(xT, dots, invn, wbf, out);
}

// Round 15
// 89.653 us; speedup vs baseline: 1.0100x; 1.0100x over previous
//
#include <hip/hip_runtime.h>
#include <hip/hip_bf16.h>
#include <float.h>

// Problem constants
#define BATCH 8
#define CHN   64
#define HW    56
#define PIX   3136          // 56*56
#define BP    25088         // BATCH*PIX (dots plane size, doubles)
#define LDB   72            // band LDS stride in bf16 elems (144 B, 16-B aligned)
#define TS    66            // dots tile stride in floats (2-way bank alias = free)
#define QW    14            // pixels per dots block (quarter row)
#define QC    18            // tile cols (QW + 4 halo)
#define NLOC  54            // 3 rows x 18 cols

typedef __bf16 bf16x8 __attribute__((ext_vector_type(8)));
typedef float  f32x4  __attribute__((ext_vector_type(4)));

static __device__ __forceinline__ unsigned short f2bf(float f) {
    unsigned int u = __float_as_uint(f);
    u += 0x7fffu + ((u >> 16) & 1u);          // round-to-nearest-even
    return (unsigned short)(u >> 16);
}

// ---------------------------------------------------------------------------
// Stage 1: dots[s][b][p], s=0..12 (13 unique slots; others are exact mirrors
// read as dots[24-s][q] downstream). fp64 products, c=0..63 sequential —
// bit-identical keys to the verified R1/R9/R12/R13 kernels.
// R15: PLANE-MAJOR layout [s][b][p] — dots stores become lane-contiguous
// coalesced wave-stores (~2 txns vs ~28 with the old [b][p][16] layout),
// and fused's select reads become 25 coalesced wave-loads. Compute/staging
// structure identical to R13 (R14's split-precision tile reverted: neutral).
// t<224 emits bf16 xT (uint2); s==12 emits invn; blocks 1792+ pack wbf.
// ---------------------------------------------------------------------------
__global__ __launch_bounds__(256) void dots_kernel(const float* __restrict__ x,
                                                   const float* __restrict__ w,
                                                   double* __restrict__ dots,
                                                   double* __restrict__ invn,
                                                   unsigned short* __restrict__ wbf,
                                                   unsigned short* __restrict__ xT) {
    const int blk = blockIdx.x;
    const int t = threadIdx.x;
    if (blk >= 1792) {                            // 16 tail blocks: pack wbf
        int wi = (blk - 1792) * 256 + t;          // 0..4095
        #pragma unroll
        for (int k = 0; k < 9; k++) {
            int l = wi + k * 4096;                // l = (o*9+tap)*64 + c
            int otap = l >> 6, c = l & 63;
            int o = otap / 9, tap = otap - o * 9;
            wbf[l] = f2bf(w[(o * CHN + c) * 9 + tap]);
        }
        return;
    }
    const int quarter = blk & 3;
    const int r = (blk >> 2) % HW;
    const int b = blk / 224;
    const int jbase = quarter * QW;

    __shared__ float tile[NLOC * TS];             // 14.3 KB
    // stage rows r-2..r, cols jbase-2..jbase+15 (zero-padded OOB)
    const float* xb = x + (size_t)b * CHN * PIX;
    for (int l = t; l < NLOC * CHN; l += 256) {
        int c = l / NLOC, rem = l - c * NLOC;
        int lr = rem / QC, lc = rem - lr * QC;
        int row = r - 2 + lr;
        int col = jbase - 2 + lc;
        float v = 0.0f;
        if (row >= 0 && row < HW && col >= 0 && col < HW)
            v = xb[(size_t)c * PIX + row * HW + col];
        tile[rem * TS + c] = v;
    }
    __syncthreads();

    // xT emit: t<224: jl = t>>4 (0..13), oct = t&15 -> 4 channels
    if (t < 224) {
        const int jl = t >> 4, oct = t & 15;
        const float* src = &tile[(2 * QC + 2 + jl) * TS + oct * 4];
        float2 f0 = *(const float2*)(src);
        float2 f1 = *(const float2*)(src + 2);
        uint2 pk;
        pk.x = (unsigned int)f2bf(f0.x) | ((unsigned int)f2bf(f0.y) << 16);
        pk.y = (unsigned int)f2bf(f1.x) | ((unsigned int)f2bf(f1.y) << 16);
        *(uint2*)(xT + ((size_t)b * PIX + r * HW + jbase + jl) * CHN + oct * 4) = pk;
    }

    if (t >= 182) return;
    const int s = t / QW;                         // 0..12
    const int jl = t - s * QW;                    // local col 0..13
    const int lr = s / 5;                         // dr = lr-2 in {-2,-1,0}
    const int dc = s % 5 - 2;
    const float* ctr = &tile[(2 * QC + 2 + jl) * TS];
    const float* nbr = &tile[(lr * QC + jl + dc + 2) * TS];

    double acc = 0.0;
    #pragma unroll 8
    for (int k = 0; k < 32; k++) {
        float2 cv = *(const float2*)(ctr + 2 * k);
        float2 nv = *(const float2*)(nbr + 2 * k);
        acc += (double)cv.x * (double)nv.x;       // c = 2k
        acc += (double)cv.y * (double)nv.y;       // c = 2k+1 (sequential order kept)
    }
    const int p = r * HW + jbase + jl;
    dots[(size_t)s * BP + b * PIX + p] = acc;     // plane-major: coalesced in jl
    if (s == 12) invn[(size_t)b * PIX + p] = 1.0 / sqrt(acc);
}

// ---------------------------------------------------------------------------
// Stage 2 (fused select + gather-conv), per (b, image row r).
// Wave 0 (t<56): 25 keys — s<13 direct dots[s][bp+p], s>=13 mirror
// dots[24-s][bp+q] (exact: IEEE mul commutes) * invn[q], DBL_MAX invalid —
// all reads lane-contiguous (coalesced) in the plane-major layout;
// 9-rank stable select + ascending index sort -> qtab. t in [56,64): zero
// qtab tail. t>=64: stage bf16 band from xT via uint4. Then
// indexed-ds_read_b128 MFMA loop, direct out write.  [R12-verified logic]
// ---------------------------------------------------------------------------
__global__ __launch_bounds__(256) void fused_kernel(const unsigned short* __restrict__ xT,
                                                    const double* __restrict__ dots,
                                                    const double* __restrict__ invn,
                                                    const unsigned short* __restrict__ wbf,
                                                    float* __restrict__ out) {
    const int b = blockIdx.y;
    const int r = blockIdx.x;
    __shared__ unsigned short band[300 * LDB];
    __shared__ int qtab[9 * 64];
    const int t = threadIdx.x;

    // A-fragments (registers; b128 loads from packed wbf)
    const int wv = t >> 6, ln = t & 63;
    const int mrow = ln & 15, kq = ln >> 4;
    const int o = wv * 16 + mrow;
    bf16x8 afr[9][2];
    #pragma unroll
    for (int tap = 0; tap < 9; tap++) {
        #pragma unroll
        for (int hf = 0; hf < 2; hf++) {
            afr[tap][hf] = *(const bf16x8*)(wbf + (size_t)(o * 9 + tap) * 64 + hf * 32 + kq * 8);
        }
    }

    if (t < 56) {
        const int jj = t;
        const int bp = b * PIX;
        const int p0 = r * HW + jj;
        const double* inb = invn + bp;
        double k2[25];
        #pragma unroll
        for (int s = 0; s < 25; s++) {
            int dr = s / 5 - 2, dc = s % 5 - 2;
            int qi = r + dr, qj = jj + dc;
            bool valid = qi >= 0 && qi < HW && qj >= 0 && qj < HW;
            int q = qi * HW + qj;
            double raw;
            if (s < 13) raw = dots[(size_t)s * BP + bp + p0];
            else        raw = valid ? dots[(size_t)(24 - s) * BP + bp + q] : 0.0;
            k2[s] = valid ? raw * inb[q] : DBL_MAX;
        }
        unsigned int used = 0;
        int bq[9];
        #pragma unroll
        for (int rr = 0; rr < 9; rr++) {
            double best = DBL_MAX; int bs = 0;
            #pragma unroll
            for (int s = 0; s < 25; s++) {
                bool ok = (((used >> s) & 1u) == 0u) && (k2[s] < best);
                if (ok) { best = k2[s]; bs = s; }
            }
            used |= (1u << bs);
            bq[rr] = (r + bs / 5 - 2) * HW + (jj + bs % 5 - 2);
        }
        #pragma unroll
        for (int a = 0; a < 8; a++) {
            #pragma unroll
            for (int c2 = 0; c2 < 8 - a; c2++) {
                int u = bq[c2], v = bq[c2 + 1];
                bq[c2] = u < v ? u : v; bq[c2 + 1] = u < v ? v : u;
            }
        }
        #pragma unroll
        for (int k = 0; k < 9; k++) {
            int q = bq[k], qi = q / HW, qj = q - qi * HW;
            qtab[k * 64 + jj] = ((qi - r + 2) * 60 + qj + 2) * LDB;
        }
    } else if (t < 64) {
        #pragma unroll
        for (int k = 0; k < 9; k++) qtab[k * 64 + t] = 0;   // tail dummy
    } else {
        // band: 300 locals x 8 ch-octs, uint4 both sides
        for (int l = t - 64; l < 2400; l += 192) {
            int local = l >> 3, ch8 = l & 7;
            int lr = local / 60, col = local - lr * 60 - 2;
            int row = r - 2 + lr;
            uint4 v = {0, 0, 0, 0};
            if (row >= 0 && row < HW && col >= 0 && col < HW)
                v = *(const uint4*)(xT + ((size_t)b * PIX + row * HW + col) * CHN + ch8 * 8);
            *(uint4*)(&band[local * LDB + ch8 * 8]) = v;
        }
    }
    __syncthreads();

    // MFMA gather-conv (verified R5/R8/R9/R12)
    f32x4 oacc[4] = {{0,0,0,0},{0,0,0,0},{0,0,0,0},{0,0,0,0}};
    #pragma unroll
    for (int tap = 0; tap < 9; tap++) {
        #pragma unroll
        for (int nt = 0; nt < 4; nt++) {
            int q = qtab[tap * 64 + nt * 16 + mrow];
            const unsigned short* bp = &band[q + kq * 8];
            bf16x8 b0 = *(const bf16x8*)bp;
            bf16x8 b1 = *(const bf16x8*)(bp + 32);
            oacc[nt] = __builtin_amdgcn_mfma_f32_16x16x32_bf16(afr[tap][0], b0, oacc[nt], 0, 0, 0);
            oacc[nt] = __builtin_amdgcn_mfma_f32_16x16x32_bf16(afr[tap][1], b1, oacc[nt], 0, 0, 0);
        }
    }
    // C/D: col = lane&15 = p-within-tile, row = kq*4+rg = o-within-strip
    float* ob = out + ((size_t)b * 64 + wv * 16 + kq * 4) * PIX + r * HW;
    #pragma unroll
    for (int nt = 0; nt < 4; nt++) {
        int p = nt * 16 + mrow;
        if (p < HW) {
            #pragma unroll
            for (int rg = 0; rg < 4; rg++) ob[(size_t)rg * PIX + p] = oacc[nt][rg];
        }
    }
}

// ---------------------------------------------------------------------------
// Workspace layout (total ~6.1 MB):
//   dots : 13 * 25088 * 8 = 2,609,152 B @ 0          (plane-major [s][b][p])
//   invn : 25088 * 8      =   200,704 B @ 2,609,152
//   wbf  : 64*9*64 * 2    =    73,728 B @ 2,809,856
//   xT   : 8*3136*64 * 2  = 3,211,264 B @ 2,883,584
// ---------------------------------------------------------------------------
extern "C" void kernel_launch(void* const* d_in, const int* in_sizes, int n_in,
                              void* d_out, int out_size, void* d_ws, size_t ws_size,
                              hipStream_t stream) {
    const float* x = (const float*)d_in[0];
    const float* w = (const float*)d_in[1];
    float* out = (float*)d_out;
    char* ws = (char*)d_ws;
    double*         dots = (double*)ws;
    double*         invn = (double*)(ws + 2609152);
    unsigned short* wbf  = (unsigned short*)(ws + 2809856);
    unsigned short* xT   = (unsigned short*)(ws + 2883584);

    // 1792 blocks cover (b,r,quarter); 16 tail blocks pack wbf
    dots_kernel<<<1808, 256, 0, stream>>>(x, w, dots, invn, wbf, xT);
    fused_kernel<<<dim3(56, 8), 256, 0, stream>>>(xT, dots, invn, wbf, out);
}